// Round 1
// baseline (880.734 us; speedup 1.0000x reference)
//
#include <hip/hip_runtime.h>
#include <math.h>

#define BB 8
#define SS 4096
#define DD 64

typedef float  f32x4 __attribute__((ext_vector_type(4)));
typedef short  s16x4 __attribute__((ext_vector_type(4)));
typedef short  s16x8 __attribute__((ext_vector_type(8)));
typedef unsigned char u8x4 __attribute__((ext_vector_type(4)));

__device__ __forceinline__ short f2bf(float f) {
  unsigned u = __builtin_bit_cast(unsigned, f);
  u += 0x7FFFu + ((u >> 16) & 1u);      // RNE to bf16 (finite values only here)
  return (short)(u >> 16);
}

// Load one 16x16x32 MFMA operand fragment from a row-major bf16 row pointer.
// lane l: elems 0-3 at col 4*g+j, elems 4-7 at col 16+4*g+j (split-half K layout).
__device__ __forceinline__ s16x8 ld_frag(const short* __restrict__ row, int g) {
  s16x4 lo = *(const s16x4*)(row + 4 * g);
  s16x4 hi = *(const s16x4*)(row + 16 + 4 * g);
  return __builtin_shufflevector(lo, hi, 0, 1, 2, 3, 4, 5, 6, 7);
}

// ---------------- kernel 1: L2-normalize q,k rows -> bf16 ----------------
__global__ __launch_bounds__(256) void k_norm(const float* __restrict__ q,
                                              const float* __restrict__ k,
                                              short* __restrict__ qn,
                                              short* __restrict__ kn) {
  const long BS = (long)BB * SS;
  long row = (long)blockIdx.x * 4 + (threadIdx.x >> 6);
  int lane = threadIdx.x & 63;
  const float* src;
  short* dst;
  if (row < BS) { src = q + row * DD; dst = qn + row * DD; }
  else          { src = k + (row - BS) * DD; dst = kn + (row - BS) * DD; }
  float x = src[lane];
  float ss = x * x;
#pragma unroll
  for (int m = 32; m >= 1; m >>= 1) ss += __shfl_xor(ss, m);
  float inv = 1.0f / (sqrtf(ss) + 1e-10f);
  dst[lane] = f2bf(x * inv);
}

// ---------------- kernel 2: V -> VT[b][d][s] bf16 ----------------
__global__ __launch_bounds__(256) void k_vtrans(const float* __restrict__ v,
                                                short* __restrict__ vt) {
  __shared__ short tile[64][65];
  int b = blockIdx.y;
  int s0 = blockIdx.x * 64;
  const float* V = v + ((long)b * SS + s0) * DD;
  int t = threadIdx.x;
#pragma unroll
  for (int i = 0; i < 16; i++) {
    int flat = t + 256 * i;            // flat = sl*64 + d
    int sl = flat >> 6, d = flat & 63;
    tile[sl][d] = f2bf(V[flat]);
  }
  __syncthreads();
  short* VT = vt + (long)b * DD * SS + s0;
#pragma unroll
  for (int i = 0; i < 16; i++) {
    int flat = t + 256 * i;            // flat = d*64 + sl
    int d = flat >> 6, sl = flat & 63;
    VT[(long)d * SS + sl] = tile[sl][d];
  }
}

// ---------------- pass A: inv row-sums of exp(scores) ----------------
// block = 256 (4 waves). All 4 waves share a 16-row q tile; each wave owns a
// 1024-wide k quarter. Swapped MFMA: S^T frag reg r holds
// score[q = q0 + (lane&15)][k = kb + 4*(lane>>4) + r]  (verified C/D map).
__global__ __launch_bounds__(256) void k_rowsum(const short* __restrict__ qn,
                                                const short* __restrict__ kn,
                                                const unsigned char* __restrict__ mask,
                                                float* __restrict__ inv_sum) {
  int b = blockIdx.y;
  int q0 = blockIdx.x * 16;
  int wid = threadIdx.x >> 6, lane = threadIdx.x & 63;
  int l15 = lane & 15, g = (lane >> 4) & 3;

  const short* Qr = qn + ((long)b * SS + q0 + l15) * DD;
  s16x8 bq0 = ld_frag(Qr, g);
  s16x8 bq1 = ld_frag(Qr + 32, g);
  const short* K = kn + (long)b * SS * DD;
  const unsigned char* M = mask + ((long)b * SS + q0 + l15) * SS;

  float acc = 0.f;
  int kend = wid * 1024 + 1024;
#pragma unroll 2
  for (int kb = wid * 1024; kb < kend; kb += 16) {
    const short* Kr = K + (long)(kb + l15) * DD;
    f32x4 c = {0.f, 0.f, 0.f, 0.f};
    c = __builtin_amdgcn_mfma_f32_16x16x32_bf16(ld_frag(Kr, g), bq0, c, 0, 0, 0);
    c = __builtin_amdgcn_mfma_f32_16x16x32_bf16(ld_frag(Kr + 32, g), bq1, c, 0, 0, 0);
    u8x4 m4 = __builtin_nontemporal_load((const u8x4*)(M + kb + 4 * g));
#pragma unroll
    for (int r = 0; r < 4; r++) acc += m4[r] ? 0.f : __expf(c[r]);
  }
  acc += __shfl_xor(acc, 16);
  acc += __shfl_xor(acc, 32);

  __shared__ float red[4][16];
  if (lane < 16) red[wid][l15] = acc;
  __syncthreads();
  if (threadIdx.x < 16) {
    float s = red[0][threadIdx.x] + red[1][threadIdx.x] +
              red[2][threadIdx.x] + red[3][threadIdx.x];
    inv_sum[(long)b * SS + q0 + threadIdx.x] = 1.0f / s;
  }
}

// ---------------- pass B: recompute scores, write P, accumulate O = P V ----
__global__ __launch_bounds__(256) void k_attn(const short* __restrict__ qn,
                                              const short* __restrict__ kn,
                                              const short* __restrict__ vt,
                                              const unsigned char* __restrict__ mask,
                                              const float* __restrict__ inv_sum,
                                              float* __restrict__ O,
                                              float* __restrict__ P) {
  int b = blockIdx.y;
  int q0 = blockIdx.x * 16;
  int wid = threadIdx.x >> 6, lane = threadIdx.x & 63;
  int l15 = lane & 15, g = (lane >> 4) & 3;

  const short* Qr = qn + ((long)b * SS + q0 + l15) * DD;
  s16x8 bq0 = ld_frag(Qr, g);
  s16x8 bq1 = ld_frag(Qr + 32, g);
  const short* K = kn + (long)b * SS * DD;
  const short* VTb = vt + (long)b * DD * SS;
  const unsigned char* M = mask + ((long)b * SS + q0 + l15) * SS;
  float inv = inv_sum[(long)b * SS + q0 + l15];
  float* Prow = P + ((long)b * SS + q0 + l15) * SS;

  f32x4 o0 = {0, 0, 0, 0}, o1 = {0, 0, 0, 0}, o2 = {0, 0, 0, 0}, o3 = {0, 0, 0, 0};

  int kend = wid * 1024 + 1024;
  for (int kb = wid * 1024; kb < kend; kb += 32) {
    const short* Kr0 = K + (long)(kb + l15) * DD;
    const short* Kr1 = K + (long)(kb + 16 + l15) * DD;
    f32x4 c0 = {0, 0, 0, 0}, c1 = {0, 0, 0, 0};
    c0 = __builtin_amdgcn_mfma_f32_16x16x32_bf16(ld_frag(Kr0, g), bq0, c0, 0, 0, 0);
    c0 = __builtin_amdgcn_mfma_f32_16x16x32_bf16(ld_frag(Kr0 + 32, g), bq1, c0, 0, 0, 0);
    c1 = __builtin_amdgcn_mfma_f32_16x16x32_bf16(ld_frag(Kr1, g), bq0, c1, 0, 0, 0);
    c1 = __builtin_amdgcn_mfma_f32_16x16x32_bf16(ld_frag(Kr1 + 32, g), bq1, c1, 0, 0, 0);

    u8x4 m0 = __builtin_nontemporal_load((const u8x4*)(M + kb + 4 * g));
    u8x4 m1 = __builtin_nontemporal_load((const u8x4*)(M + kb + 16 + 4 * g));
    f32x4 p0, p1;
#pragma unroll
    for (int r = 0; r < 4; r++) {
      p0[r] = m0[r] ? 0.f : __expf(c0[r]) * inv;
      p1[r] = m1[r] ? 0.f : __expf(c1[r]) * inv;
    }
    // write normalized P (streamed, nontemporal)
    __builtin_nontemporal_store(p0, (f32x4*)(Prow + kb + 4 * g));
    __builtin_nontemporal_store(p1, (f32x4*)(Prow + kb + 16 + 4 * g));

    // pack P fragment as PV A-operand: slots 0-3 <- tile0, slots 4-7 <- tile1
    s16x8 pa;
    pa[0] = f2bf(p0[0]); pa[1] = f2bf(p0[1]); pa[2] = f2bf(p0[2]); pa[3] = f2bf(p0[3]);
    pa[4] = f2bf(p1[0]); pa[5] = f2bf(p1[1]); pa[6] = f2bf(p1[2]); pa[7] = f2bf(p1[3]);

    o0 = __builtin_amdgcn_mfma_f32_16x16x32_bf16(pa, ld_frag(VTb + (long)(0  + l15) * SS + kb, g), o0, 0, 0, 0);
    o1 = __builtin_amdgcn_mfma_f32_16x16x32_bf16(pa, ld_frag(VTb + (long)(16 + l15) * SS + kb, g), o1, 0, 0, 0);
    o2 = __builtin_amdgcn_mfma_f32_16x16x32_bf16(pa, ld_frag(VTb + (long)(32 + l15) * SS + kb, g), o2, 0, 0, 0);
    o3 = __builtin_amdgcn_mfma_f32_16x16x32_bf16(pa, ld_frag(VTb + (long)(48 + l15) * SS + kb, g), o3, 0, 0, 0);
  }

  // cross-wave reduction of O partials (each wave covered a k quarter)
  __shared__ float red[4][16][64];
#pragma unroll
  for (int r = 0; r < 4; r++) {
    red[wid][4 * g + r][0  + l15] = o0[r];
    red[wid][4 * g + r][16 + l15] = o1[r];
    red[wid][4 * g + r][32 + l15] = o2[r];
    red[wid][4 * g + r][48 + l15] = o3[r];
  }
  __syncthreads();
  float* Ob = O + ((long)b * SS + q0) * DD;
  const float* rf = (const float*)red;
#pragma unroll
  for (int i = 0; i < 4; i++) {
    int flat = threadIdx.x + 256 * i;  // flat = q*64 + d
    Ob[flat] = rf[0 * 1024 + flat] + rf[1 * 1024 + flat] +
               rf[2 * 1024 + flat] + rf[3 * 1024 + flat];
  }
}

extern "C" void kernel_launch(void* const* d_in, const int* in_sizes, int n_in,
                              void* d_out, int out_size, void* d_ws, size_t ws_size,
                              hipStream_t stream) {
  const float* q = (const float*)d_in[0];
  const float* k = (const float*)d_in[1];
  const float* v = (const float*)d_in[2];
  const unsigned char* mask = (const unsigned char*)d_in[3];

  const long BSD = (long)BB * SS * DD;
  short* qn = (short*)d_ws;
  short* kn = qn + BSD;
  short* vtp = kn + BSD;
  float* inv_sum = (float*)(vtp + BSD);

  float* O = (float*)d_out;
  float* P = O + BSD;

  // 1) normalize q,k -> bf16
  k_norm<<<dim3(2 * BB * SS / 4), dim3(256), 0, stream>>>(q, k, qn, kn);
  // 2) transpose V -> bf16 VT[b][d][s]
  k_vtrans<<<dim3(SS / 64, BB), dim3(256), 0, stream>>>(v, vtp);
  // 3) pass A: inverse row sums
  k_rowsum<<<dim3(SS / 16, BB), dim3(256), 0, stream>>>(qn, kn, mask, inv_sum);
  // 4) pass B: P + O
  k_attn<<<dim3(SS / 16, BB), dim3(256), 0, stream>>>(qn, kn, vtp, mask, inv_sum, O, P);
}

// Round 2
// 252.708 us; speedup vs baseline: 3.4852x; 3.4852x over previous
//
#include <hip/hip_runtime.h>
#include <math.h>

#define BB 8
#define SS 4096
#define DD 64
#define NT (SS / 64)

typedef float  f32x4 __attribute__((ext_vector_type(4)));
typedef short  s16x4 __attribute__((ext_vector_type(4)));
typedef short  s16x8 __attribute__((ext_vector_type(8)));
typedef unsigned char u8x16 __attribute__((ext_vector_type(16)));

__device__ __forceinline__ short f2bf(float f) {
  unsigned u = __builtin_bit_cast(unsigned, f);
  u += 0x7FFFu + ((u >> 16) & 1u);
  return (short)(u >> 16);
}

// ---------------- kernel 1: L2-normalize q,k rows -> bf16 ----------------
__global__ __launch_bounds__(256) void k_norm(const float* __restrict__ q,
                                              const float* __restrict__ k,
                                              short* __restrict__ qn,
                                              short* __restrict__ kn) {
  const long BS = (long)BB * SS;
  long row = (long)blockIdx.x * 4 + (threadIdx.x >> 6);
  int lane = threadIdx.x & 63;
  const float* src;
  short* dst;
  if (row < BS) { src = q + row * DD; dst = qn + row * DD; }
  else          { src = k + (row - BS) * DD; dst = kn + (row - BS) * DD; }
  float x = src[lane];
  float ss = x * x;
#pragma unroll
  for (int m = 32; m >= 1; m >>= 1) ss += __shfl_xor(ss, m);
  float inv = 1.0f / (sqrtf(ss) + 1e-10f);
  dst[lane] = f2bf(x * inv);
}

// ---------------- kernel 2: V -> VT[b][d][s] bf16 ----------------
__global__ __launch_bounds__(256) void k_vtrans(const float* __restrict__ v,
                                                short* __restrict__ vt) {
  __shared__ short tile[64][65];
  int b = blockIdx.y;
  int s0 = blockIdx.x * 64;
  const float* V = v + ((long)b * SS + s0) * DD;
  int t = threadIdx.x;
#pragma unroll
  for (int i = 0; i < 16; i++) {
    int flat = t + 256 * i;            // flat = sl*64 + d
    int sl = flat >> 6, d = flat & 63;
    tile[sl][d] = f2bf(V[flat]);
  }
  __syncthreads();
  short* VT = vt + (long)b * DD * SS + s0;
#pragma unroll
  for (int i = 0; i < 16; i++) {
    int flat = t + 256 * i;            // flat = d*64 + sl
    int d = flat >> 6, sl = flat & 63;
    VT[(long)d * SS + sl] = tile[sl][d];
  }
}

// ---------------- kernel 3: mask bytes -> bits (16x compress) ----------------
__global__ __launch_bounds__(256) void k_maskbits(const unsigned char* __restrict__ m,
                                                  unsigned short* __restrict__ bits) {
  long gid = (long)blockIdx.x * 256 + threadIdx.x;
  u8x16 v = __builtin_nontemporal_load((const u8x16*)(m + gid * 16));
  unsigned r = 0;
#pragma unroll
  for (int i = 0; i < 16; i++) r |= (v[i] ? 1u : 0u) << i;
  __builtin_nontemporal_store((unsigned short)r, bits + gid);
}

// ---------------- pass A: inverse row sums of exp(scores) ----------------
// 4 waves/block, wave = 16 q rows, full K sweep; K tile double-buffered in LDS.
__global__ __launch_bounds__(256) void k_rowsum(const short* __restrict__ qn,
                                                const short* __restrict__ kn,
                                                const unsigned short* __restrict__ bits,
                                                float* __restrict__ inv_sum) {
  __shared__ __align__(16) short Kt[2][4096];
  int b = blockIdx.x & 7;
  int q0 = (blockIdx.x >> 3) << 6;
  int wid = threadIdx.x >> 6, lane = threadIdx.x & 63;
  int l15 = lane & 15, g = lane >> 4;
  int qr = q0 + (wid << 4);

  const short* Qr = qn + ((long)(b * SS) + qr + l15) * DD;
  s16x8 qf0 = *(const s16x8*)(Qr + 8 * g);
  s16x8 qf1 = *(const s16x8*)(Qr + 32 + 8 * g);

  const short* Kb = kn + (long)b * SS * DD;
  const unsigned long long* B64 =
      (const unsigned long long*)bits + ((long)(b * SS) + qr + l15) * (SS / 64);

  int sr = lane >> 3, sc = lane & 7;
  int r0 = (wid << 4) + sr, r1 = r0 + 8;
  const short* Ksrc0 = Kb + (long)r0 * DD + sc * 8;
  const short* Ksrc1 = Kb + (long)r1 * DD + sc * 8;
  int kd0 = r0 * DD + ((sc ^ sr) << 3);
  int kd1 = r1 * DD + ((sc ^ sr) << 3);

  // prologue: stage tile 0
  s16x8 kst0 = *(const s16x8*)Ksrc0;
  s16x8 kst1 = *(const s16x8*)Ksrc1;
  *(s16x8*)&Kt[0][kd0] = kst0;
  *(s16x8*)&Kt[0][kd1] = kst1;
  __syncthreads();

  float acc = 0.f;
  int cur = 0;
  int swk = (l15 & 7);
  for (int t = 0; t < NT; ++t) {
    if (t + 1 < NT) {
      long koff = (long)(t + 1) * 64 * DD;
      kst0 = *(const s16x8*)(Ksrc0 + koff);
      kst1 = *(const s16x8*)(Ksrc1 + koff);
    }
    unsigned long long w64 = B64[t];
    const short* Kc = &Kt[cur][0];
#pragma unroll
    for (int tt = 0; tt < 4; ++tt) {
      const short* krow = Kc + ((tt << 4) + l15) * DD;
      s16x8 a0 = *(const s16x8*)(krow + ((g ^ swk) << 3));
      s16x8 a1 = *(const s16x8*)(krow + (((4 + g) ^ swk) << 3));
      f32x4 c = {0.f, 0.f, 0.f, 0.f};
      c = __builtin_amdgcn_mfma_f32_16x16x32_bf16(a0, qf0, c, 0, 0, 0);
      c = __builtin_amdgcn_mfma_f32_16x16x32_bf16(a1, qf1, c, 0, 0, 0);
#pragma unroll
      for (int r = 0; r < 4; ++r) {
        unsigned bit = (unsigned)(w64 >> ((tt << 4) + (g << 2) + r)) & 1u;
        acc += bit ? 0.f : __expf(c[r]);
      }
    }
    if (t + 1 < NT) {
      short* Kd = &Kt[cur ^ 1][0];
      *(s16x8*)(Kd + kd0) = kst0;
      *(s16x8*)(Kd + kd1) = kst1;
    }
    __syncthreads();
    cur ^= 1;
  }
  acc += __shfl_xor(acc, 16);
  acc += __shfl_xor(acc, 32);
  if (lane < 16) inv_sum[(long)b * SS + qr + l15] = 1.0f / acc;
}

// ---------------- pass B: recompute scores, write P, accumulate O ----------------
__global__ __launch_bounds__(256) void k_attn(const short* __restrict__ qn,
                                              const short* __restrict__ kn,
                                              const short* __restrict__ vt,
                                              const unsigned short* __restrict__ bits,
                                              const float* __restrict__ inv_sum,
                                              float* __restrict__ O,
                                              float* __restrict__ P) {
  __shared__ __align__(16) short Kt[2][4096];
  __shared__ __align__(16) short Vt[2][4096];
  int b = blockIdx.x & 7;
  int q0 = (blockIdx.x >> 3) << 6;
  int wid = threadIdx.x >> 6, lane = threadIdx.x & 63;
  int l15 = lane & 15, g = lane >> 4;
  int qr = q0 + (wid << 4);

  const short* Qr = qn + ((long)(b * SS) + qr + l15) * DD;
  s16x8 qf0 = *(const s16x8*)(Qr + 8 * g);
  s16x8 qf1 = *(const s16x8*)(Qr + 32 + 8 * g);

  const short* Kb = kn + (long)b * SS * DD;
  const short* Vb = vt + (long)b * DD * SS;
  const unsigned long long* B64 =
      (const unsigned long long*)bits + ((long)(b * SS) + qr + l15) * (SS / 64);
  float inv = inv_sum[(long)b * SS + qr + l15];
  float linv = __logf(inv);
  float* Prow = P + ((long)(b * SS) + qr + l15) * SS;

  int sr = lane >> 3, sc = lane & 7;
  int r0 = (wid << 4) + sr, r1 = r0 + 8;
  const short* Ksrc0 = Kb + (long)r0 * DD + sc * 8;
  const short* Ksrc1 = Kb + (long)r1 * DD + sc * 8;
  const short* Vsrc0 = Vb + (long)r0 * SS + sc * 8;   // d-row r0, s chunk sc
  const short* Vsrc1 = Vb + (long)r1 * SS + sc * 8;
  int sd0 = r0 * DD + ((sc ^ sr) << 3);
  int sd1 = r1 * DD + ((sc ^ sr) << 3);

  // prologue: stage tile 0
  s16x8 kst0 = *(const s16x8*)Ksrc0;
  s16x8 kst1 = *(const s16x8*)Ksrc1;
  s16x8 vst0 = *(const s16x8*)Vsrc0;
  s16x8 vst1 = *(const s16x8*)Vsrc1;
  *(s16x8*)&Kt[0][sd0] = kst0;
  *(s16x8*)&Kt[0][sd1] = kst1;
  *(s16x8*)&Vt[0][sd0] = vst0;
  *(s16x8*)&Vt[0][sd1] = vst1;
  __syncthreads();

  f32x4 o0 = {0, 0, 0, 0}, o1 = {0, 0, 0, 0}, o2 = {0, 0, 0, 0}, o3 = {0, 0, 0, 0};
  int cur = 0;
  int swk = (l15 & 7);
  for (int t = 0; t < NT; ++t) {
    if (t + 1 < NT) {
      long koff = (long)(t + 1) * 64 * DD;
      kst0 = *(const s16x8*)(Ksrc0 + koff);
      kst1 = *(const s16x8*)(Ksrc1 + koff);
      vst0 = *(const s16x8*)(Vsrc0 + (t + 1) * 64);
      vst1 = *(const s16x8*)(Vsrc1 + (t + 1) * 64);
    }
    unsigned long long w64 = B64[t];
    const short* Kc = &Kt[cur][0];
    const short* Vc = &Vt[cur][0];

    f32x4 p[4];
#pragma unroll
    for (int tt = 0; tt < 4; ++tt) {
      const short* krow = Kc + ((tt << 4) + l15) * DD;
      s16x8 a0 = *(const s16x8*)(krow + ((g ^ swk) << 3));
      s16x8 a1 = *(const s16x8*)(krow + (((4 + g) ^ swk) << 3));
      f32x4 c = {0.f, 0.f, 0.f, 0.f};
      c = __builtin_amdgcn_mfma_f32_16x16x32_bf16(a0, qf0, c, 0, 0, 0);
      c = __builtin_amdgcn_mfma_f32_16x16x32_bf16(a1, qf1, c, 0, 0, 0);
#pragma unroll
      for (int r = 0; r < 4; ++r) {
        unsigned bit = (unsigned)(w64 >> ((tt << 4) + (g << 2) + r)) & 1u;
        p[tt][r] = bit ? 0.f : __expf(c[r] + linv);
      }
      __builtin_nontemporal_store(p[tt],
          (f32x4*)(Prow + (t << 6) + (tt << 4) + (g << 2)));
    }

    s16x8 pa0, pa1;
#pragma unroll
    for (int j = 0; j < 4; ++j) {
      pa0[j] = f2bf(p[0][j]); pa0[4 + j] = f2bf(p[1][j]);
      pa1[j] = f2bf(p[2][j]); pa1[4 + j] = f2bf(p[3][j]);
    }

#pragma unroll
    for (int n = 0; n < 4; ++n) {
      const short* vrow = Vc + ((n << 4) + l15) * DD;
      int g2 = g >> 1, hh = (g & 1) << 2;
      s16x4 lo0 = *(const s16x4*)(vrow + (((g2    ) ^ swk) << 3) + hh);
      s16x4 hi0 = *(const s16x4*)(vrow + (((g2 + 2) ^ swk) << 3) + hh);
      s16x4 lo1 = *(const s16x4*)(vrow + (((g2 + 4) ^ swk) << 3) + hh);
      s16x4 hi1 = *(const s16x4*)(vrow + (((g2 + 6) ^ swk) << 3) + hh);
      s16x8 vf0 = __builtin_shufflevector(lo0, hi0, 0, 1, 2, 3, 4, 5, 6, 7);
      s16x8 vf1 = __builtin_shufflevector(lo1, hi1, 0, 1, 2, 3, 4, 5, 6, 7);
      f32x4* on = (n == 0) ? &o0 : (n == 1) ? &o1 : (n == 2) ? &o2 : &o3;
      *on = __builtin_amdgcn_mfma_f32_16x16x32_bf16(pa0, vf0, *on, 0, 0, 0);
      *on = __builtin_amdgcn_mfma_f32_16x16x32_bf16(pa1, vf1, *on, 0, 0, 0);
    }

    if (t + 1 < NT) {
      short* Kd = &Kt[cur ^ 1][0];
      short* Vd = &Vt[cur ^ 1][0];
      *(s16x8*)(Kd + sd0) = kst0;
      *(s16x8*)(Kd + sd1) = kst1;
      *(s16x8*)(Vd + sd0) = vst0;
      *(s16x8*)(Vd + sd1) = vst1;
    }
    __syncthreads();
    cur ^= 1;
  }

  float* Ob = O + ((long)(b * SS) + qr) * DD;
#pragma unroll
  for (int r = 0; r < 4; ++r) {
    int row = (g << 2) + r;
    Ob[row * DD +  0 + l15] = o0[r];
    Ob[row * DD + 16 + l15] = o1[r];
    Ob[row * DD + 32 + l15] = o2[r];
    Ob[row * DD + 48 + l15] = o3[r];
  }
}

extern "C" void kernel_launch(void* const* d_in, const int* in_sizes, int n_in,
                              void* d_out, int out_size, void* d_ws, size_t ws_size,
                              hipStream_t stream) {
  const float* q = (const float*)d_in[0];
  const float* k = (const float*)d_in[1];
  const float* v = (const float*)d_in[2];
  const unsigned char* mask = (const unsigned char*)d_in[3];

  const long BSD = (long)BB * SS * DD;            // 2M elems
  short* qn = (short*)d_ws;
  short* kn = qn + BSD;
  short* vtp = kn + BSD;
  float* inv_sum = (float*)(vtp + BSD);
  unsigned short* bits = (unsigned short*)(inv_sum + (long)BB * SS);

  float* O = (float*)d_out;
  float* P = O + BSD;

  k_norm<<<dim3(2 * BB * SS / 4), dim3(256), 0, stream>>>(q, k, qn, kn);
  k_vtrans<<<dim3(SS / 64, BB), dim3(256), 0, stream>>>(v, vtp);
  k_maskbits<<<dim3((int)((long)BB * SS * SS / 16 / 256)), dim3(256), 0, stream>>>(mask, bits);
  k_rowsum<<<dim3(BB * SS / 64), dim3(256), 0, stream>>>(qn, kn, bits, inv_sum);
  k_attn<<<dim3(BB * SS / 64), dim3(256), 0, stream>>>(qn, kn, vtp, bits, inv_sum, O, P);
}